// Round 5
// baseline (373.834 us; speedup 1.0000x reference)
//
#include <hip/hip_runtime.h>
#include <stdint.h>

// out[b,o,h,w] = sum_c x[b,c,h,w] * Wg[(h%4)*4+(w%4), o, c]
// B=16, Cs=Ct=512, H=W=64.
// Round-6b (resubmit; round-6 bench died on container infra, no verdict):
//   register-direct GEMM. Key insight: in this grouped decomposition LDS
//   tiles are wave-private (each wave owns its (q, m-slice)); LDS bought no
//   reuse, only barriers. With xT[r][q][rg][w16][c] bf16 (pre-pass) both
//   A and B MFMA fragments load straight from global into registers:
//   fragment = lanes(qd,lr) reading 16B each = 16 full 64B lines, coalesced.
//   Main loop: 12 global_load_dwordx4 + 32 MFMA per wave/step. No LDS, no
//   barriers, no vmcnt choreography. Reuse lives in L2/L3; XCD-aware block
//   decode co-locates the 8 mb-siblings sharing each B slice on one XCD.
//   Blocks: 256 thr (4 waves = 4 q), wave tile M=64 x N=128, grid 1024 1-D,
//   2 blocks/CU (LDS 34KB epilogue-only). Epilogue LDS-transpose unchanged.

typedef __attribute__((ext_vector_type(8))) short short8;
typedef __attribute__((ext_vector_type(4))) float f32x4;

#define CS 512
#define CT 512
#define HW 4096

__device__ __forceinline__ uint16_t f32_to_bf16(float f) {
    uint32_t u = __builtin_bit_cast(uint32_t, f);
    u += 0x7FFFu + ((u >> 16) & 1u);     // RNE
    return (uint16_t)(u >> 16);
}

__global__ __launch_bounds__(256)
void w2_cvt(const float* __restrict__ Wg, uint16_t* __restrict__ W2) {
    int idx = (blockIdx.x * 256 + threadIdx.x) * 8;
    float4 a = *(const float4*)(Wg + idx);
    float4 b = *(const float4*)(Wg + idx + 4);
    uint16_t o[8];
    o[0]=f32_to_bf16(a.x); o[1]=f32_to_bf16(a.y); o[2]=f32_to_bf16(a.z); o[3]=f32_to_bf16(a.w);
    o[4]=f32_to_bf16(b.x); o[5]=f32_to_bf16(b.y); o[6]=f32_to_bf16(b.z); o[7]=f32_to_bf16(b.w);
    *(short8*)(W2 + idx) = *(short8*)o;
}

// x[b,c,h,w] f32  ->  xT[r][q][rg=b*16+h4][w16][c] bf16  (67 MB)
// block: (c-tile, h, b); 64c x 64w tile through LDS.  ~at BW roofline.
__global__ __launch_bounds__(256)
void xt_cvt(const float* __restrict__ x, uint16_t* __restrict__ xT) {
    const int c0 = blockIdx.x * 64;
    const int h  = blockIdx.y;
    const int b  = blockIdx.z;
    const int r = h & 3, h4 = h >> 2, rg = b * 16 + h4;
    __shared__ float L[64][65];
    const int tid = threadIdx.x;
    const int wr = tid & 15;        // w float4 chunk
    const int cr = tid >> 4;        // c row (16 per iter)
    const float* src = x + (((size_t)b * CS + c0 + cr) * 64 + h) * 64 + wr * 4;
    #pragma unroll
    for (int it = 0; it < 4; ++it) {
        float4 v = *(const float4*)(src + (size_t)it * 16 * HW);
        L[cr + it * 16][wr * 4 + 0] = v.x;
        L[cr + it * 16][wr * 4 + 1] = v.y;
        L[cr + it * 16][wr * 4 + 2] = v.z;
        L[cr + it * 16][wr * 4 + 3] = v.w;
    }
    __syncthreads();
    const int orow = tid >> 2;            // 0..63
    const int q = orow >> 4, w16 = orow & 15;
    const int cc = (tid & 3) * 16;
    const int w = w16 * 4 + q;
    uint16_t tmp[16];
    #pragma unroll
    for (int i = 0; i < 16; ++i) tmp[i] = f32_to_bf16(L[cc + i][w]);
    uint16_t* dst = xT + ((((size_t)(r * 4 + q) * 256 + rg) * 16 + w16) * 512 + c0 + cc);
    *(short8*)(dst)     = *(short8*)(tmp);
    *(short8*)(dst + 8) = *(short8*)(tmp + 8);
}

__global__ __launch_bounds__(256, 2)
void gwl_main(const uint16_t* __restrict__ W2, const uint16_t* __restrict__ xT,
              float* __restrict__ out) {
    // XCD-aware 1-D decode: blocks sharing (nb, r) [same B slice] get the
    // same (id % 8) -> same XCD under round-robin dispatch.
    const int l  = blockIdx.x;            // 0..1023
    const int x3 = l & 7;
    const int t  = l >> 3;                // 0..127
    const int mb = t >> 4;                // 0..7
    const int combo = (t & 15) * 8 + x3;  // 0..127
    const int nb = combo >> 2;            // 0..31
    const int r  = combo & 3;
    const int m0 = mb * 64;

    const int tid  = threadIdx.x;
    const int lane = tid & 63;
    const int q    = tid >> 6;            // wave = q phase
    const int lr = lane & 15, qd = lane >> 4;

    // Fragment bases (wave-uniform) + per-lane 32-bit byte offsets.
    // afr[i]: A row m0+i*16+lr, k-chunk qd  (row stride CS*2 = 1KB)
    // bfr[j]: pixel row (nb*8+j)*16+lr of xT's [rg][w16][c], k-chunk qd
    const uint16_t* Abase = W2 + ((size_t)(r * 4 + q) * CT + m0) * CS;
    const uint16_t* Bbase = xT + ((size_t)(r * 4 + q) * 256 + nb * 8) * 16 * 512;
    int voA[4], voB[8];
    #pragma unroll
    for (int i = 0; i < 4; ++i) voA[i] = (((i * 16 + lr) * CS) + qd * 8) * 2;
    #pragma unroll
    for (int j = 0; j < 8; ++j) voB[j] = (((j * 16 + lr) * 512) + qd * 8) * 2;

    f32x4 acc[4][8] = {};
    short8 a0[4], b0[8], a1[4], b1[8];

    auto LD = [&](short8* A, short8* B, int k) {
        const int kb = k * 64;            // k*32 elems * 2B; <=960, folds to imm
        #pragma unroll
        for (int i = 0; i < 4; ++i)
            A[i] = *(const short8*)((const char*)Abase + voA[i] + kb);
        #pragma unroll
        for (int j = 0; j < 8; ++j)
            B[j] = *(const short8*)((const char*)Bbase + voB[j] + kb);
    };
    auto FM = [&](const short8* A, const short8* B) {
        #pragma unroll
        for (int i = 0; i < 4; ++i)
            #pragma unroll
            for (int j = 0; j < 8; ++j)
                acc[i][j] = __builtin_amdgcn_mfma_f32_16x16x32_bf16(
                    A[i], B[j], acc[i][j], 0, 0, 0);
    };

    LD(a0, b0, 0);
    LD(a1, b1, 1);
    #pragma unroll
    for (int kp = 0; kp < 8; ++kp) {
        if (kp < 7) {
            FM(a0, b0); LD(a0, b0, 2 * kp + 2);   // a0/b0 free; loads fly under FM(a1)
            FM(a1, b1); LD(a1, b1, 2 * kp + 3);
        } else {
            FM(a0, b0);
            FM(a1, b1);
        }
    }

    // ---- epilogue: LDS transpose -> full-line float4 stores
    // acc[i][j][g]: m = m0 + i*16 + qd*4+g, pixel n = j*16+lr
    //   -> rho = j, w16 = lr, w = lr*4 + q.
    __shared__ __align__(16) float T[16 * 8 * 68];   // 34816 B
    const int m16s = tid >> 4;          // 0..15
    const int rsub = tid & 15;
    const int rs   = rsub >> 1;         // 0..7
    const int ws   = (rsub & 1) * 32;   // 0 or 32 floats
    const int rgs  = nb * 8 + rs;
    const int obb  = rgs >> 4;
    const int oh4  = rgs & 15;
    #pragma unroll
    for (int ic = 0; ic < 4; ++ic) {
        __syncthreads();                 // prior reads of T done
        #pragma unroll
        for (int j = 0; j < 8; ++j)
            #pragma unroll
            for (int g = 0; g < 4; ++g)
                T[((qd * 4 + g) * 8 + j) * 68 + lr * 4 + q] = acc[ic][j][g];
        __syncthreads();
        float* op = out + ((size_t)obb * CT + m0 + ic * 16 + m16s) * HW
                        + (oh4 * 4 + r) * 64 + ws;
        const float* tp = T + (m16s * 8 + rs) * 68 + ws;
        #pragma unroll
        for (int c = 0; c < 8; ++c)
            ((float4*)op)[c] = ((const float4*)tp)[c];
    }
}

// ---------- fallback (workspace too small): round-2 self-contained kernel ----
#define MT 128
#define NR 8
#define BK 32
#define BPITCH 40
#define FBUFB 73728

__global__ __launch_bounds__(512, 2)
void gwl_fb(const float* __restrict__ x, const float* __restrict__ Wg,
            float* __restrict__ out) {
    const int nb = blockIdx.x, mb = blockIdx.y, r = blockIdx.z;
    const int m0 = mb * MT;
    __shared__ __align__(16) unsigned char smem[2 * FBUFB];
    float* T = (float*)smem;
    const int tid = threadIdx.x, lane = tid & 63, wave = tid >> 6;
    const int q = wave & 3, mw = wave >> 2;
    const int lr = lane & 15, qd = lane >> 4;
    const int w16 = tid & 15, rho = (tid >> 4) & 7, kw = tid >> 7;
    const int rg = nb * NR + rho, bb = rg >> 4, h4 = rg & 15;
    const float* bbase = x + (size_t)bb * CS * HW
                           + (size_t)((h4 * 4 + r) * 64 + w16 * 4);
    float4 breg[8];
    auto loadB = [&](int k0) {
        const float* p = bbase + (size_t)(k0 + kw * 8) * HW;
        #pragma unroll
        for (int cc = 0; cc < 8; ++cc) breg[cc] = *(const float4*)(p + (size_t)cc * HW);
    };
    auto writeB = [&](uint16_t* BsD) {
        #pragma unroll
        for (int qq = 0; qq < 4; ++qq) {
            uint16_t tmp[8];
            #pragma unroll
            for (int cc = 0; cc < 8; ++cc)
                tmp[cc] = f32_to_bf16(((const float*)&breg[cc])[qq]);
            *(short8*)(BsD + (qq * 128 + rho * 16 + w16) * BPITCH + kw * 8) = *(short8*)tmp;
        }
    };
    auto stageA = [&](int k0, uint16_t* AsD) {
        const int qa = tid >> 7, rem = tid & 127;
        const int ka = rem & 7, ma = rem >> 3;
        const float* ap = Wg + ((size_t)(r * 4 + qa) * CT + m0 + ma) * CS + k0 + ka * 4;
        const int kc = (((ka >> 1) ^ ((ma >> 1) & 3)) * 8) + (ka & 1) * 4;
        #pragma unroll
        for (int it = 0; it < 8; ++it) {
            float4 v = *(const float4*)(ap + (size_t)it * 16 * CS);
            uint16_t tmp[4] = {f32_to_bf16(v.x), f32_to_bf16(v.y),
                               f32_to_bf16(v.z), f32_to_bf16(v.w)};
            *(uint64_t*)(AsD + (qa * 128 + ma + it * 16) * 32 + kc) =
                *(const uint64_t*)tmp;
        }
    };
    f32x4 acc[4][8] = {};
    {
        uint16_t* As0 = (uint16_t*)smem;
        uint16_t* Bs0 = (uint16_t*)(smem + 32768);
        loadB(0);
        stageA(0, As0);
        writeB(Bs0);
        loadB(BK);
        __syncthreads();
    }
    for (int k = 0; k < 16; ++k) {
        const uint16_t* Asq = (const uint16_t*)(smem + (k & 1) * FBUFB)
                              + (q * 128 + mw * 64) * 32;
        const uint16_t* Bsq = (const uint16_t*)(smem + (k & 1) * FBUFB + 32768)
                              + q * 128 * BPITCH;
        short8 afr[4], bfr[8];
        #pragma unroll
        for (int i = 0; i < 4; ++i)
            afr[i] = *(const short8*)(Asq + (i * 16 + lr) * 32
                                      + ((qd ^ ((lr >> 1) & 3)) * 8));
        #pragma unroll
        for (int j = 0; j < 8; ++j)
            bfr[j] = *(const short8*)(Bsq + (j * 16 + lr) * BPITCH + qd * 8);
        if (k < 15) {
            uint16_t* AsN = (uint16_t*)(smem + ((k + 1) & 1) * FBUFB);
            uint16_t* BsN = (uint16_t*)(smem + ((k + 1) & 1) * FBUFB + 32768);
            stageA((k + 1) * BK, AsN);
            writeB(BsN);
            if (k < 14) loadB((k + 2) * BK);
        }
        #pragma unroll
        for (int i = 0; i < 4; ++i)
            #pragma unroll
            for (int j = 0; j < 8; ++j)
                acc[i][j] = __builtin_amdgcn_mfma_f32_16x16x32_bf16(
                    afr[i], bfr[j], acc[i][j], 0, 0, 0);
        if (k < 15) {
            asm volatile("s_waitcnt vmcnt(0)" ::: "memory");
            asm volatile("s_waitcnt lgkmcnt(0)" ::: "memory");
            __builtin_amdgcn_s_barrier();
        }
    }
    const int m16s = tid >> 5, rs = (tid >> 2) & 7, ws = (tid & 3) * 16;
    const int rgs = nb * NR + rs, obb = rgs >> 4, oh4 = rgs & 15;
    #pragma unroll
    for (int ic = 0; ic < 8; ++ic) {
        __syncthreads();
        if (mw == (ic >> 2)) {
            const int i = ic & 3;
            #pragma unroll
            for (int j = 0; j < 8; ++j)
                #pragma unroll
                for (int g = 0; g < 4; ++g)
                    T[((qd * 4 + g) * 8 + j) * 68 + lr * 4 + q] = acc[i][j][g];
        }
        __syncthreads();
        float* op = out + ((size_t)obb * CT + m0 + ic * 16 + m16s) * HW
                        + (oh4 * 4 + r) * 64 + ws;
        const float* tp = T + (m16s * 8 + rs) * 68 + ws;
        #pragma unroll
        for (int c = 0; c < 4; ++c)
            ((float4*)op)[c] = ((const float4*)tp)[c];
    }
}

extern "C" void kernel_launch(void* const* d_in, const int* in_sizes, int n_in,
                              void* d_out, int out_size, void* d_ws, size_t ws_size,
                              hipStream_t stream) {
    const float* x  = (const float*)d_in[0];
    const float* Wg = (const float*)d_in[1];
    float* out = (float*)d_out;
    const size_t w2_elems = (size_t)16 * 512 * 512;             // 8 MB
    const size_t xt_elems = (size_t)4 * 4 * 256 * 16 * 512;     // 67 MB
    if (ws_size >= (w2_elems + xt_elems) * 2) {
        uint16_t* W2 = (uint16_t*)d_ws;
        uint16_t* xT = (uint16_t*)d_ws + w2_elems;
        w2_cvt<<<2048, 256, 0, stream>>>(Wg, W2);
        xt_cvt<<<dim3(8, 64, 16), 256, 0, stream>>>(x, xT);
        gwl_main<<<1024, 256, 0, stream>>>(W2, xT, out);
    } else {
        gwl_fb<<<dim3(32, 4, 4), 512, 0, stream>>>(x, Wg, out);
    }
}

// Round 7
// 322.929 us; speedup vs baseline: 1.1576x; 1.1576x over previous
//
#include <hip/hip_runtime.h>
#include <stdint.h>

// out[b,o,h,w] = sum_c x[b,c,h,w] * Wg[(h%4)*4+(w%4), o, c]
// B=16, Cs=Ct=512, H=W=64.
// Round-7b (resubmit; round-7 bench died on container infra twice, no
// verdict; kernel audited for barrier-divergence/deadlock — none found):
//   revert to round-5 (93us) glds+LDS structure; fix its exposed ds_read
//   latency. Old: reads -> forced lgkmcnt(0)+sched_barrier(0) -> barrier ->
//   stage -> 32 MFMA (full drain before ANY MFMA = m233 2-phase stall).
//   New: reads -> MFMA half-A (16, compiler fine-lgkm interleave covers
//   read latency) -> lgkm0+barrier (Bs cross-wave safety) -> stage(k+2) ->
//   MFMA half-B (16, overlaps glds issue) -> vmcnt(8)+barrier.
//   setprio around each half (T5; wave phase diversity now exists).
//   Register-direct variant (round-6) measured 146us latency-bound: VGPR
//   caps per-wave pipeline depth; LDS+glds with counted vmcnt stays.

typedef __attribute__((ext_vector_type(8))) short short8;
typedef __attribute__((ext_vector_type(4))) float f32x4;

#define CS 512
#define CT 512
#define HW 4096
#define BK 32
#define MT 128       // out-channel rows per block
#define NR 8         // pixel rows per block
#define ABYTES 32768 // As: 4q * 128m * 32k bf16
#define BBYTES 32768 // Bs: 4q * 128n * 32k bf16
#define BUFB (ABYTES + BBYTES)

__device__ __forceinline__ uint16_t f32_to_bf16(float f) {
    uint32_t u = __builtin_bit_cast(uint32_t, f);
    u += 0x7FFFu + ((u >> 16) & 1u);     // RNE
    return (uint16_t)(u >> 16);
}

__global__ __launch_bounds__(256)
void w2_cvt(const float* __restrict__ Wg, uint16_t* __restrict__ W2) {
    int idx = (blockIdx.x * 256 + threadIdx.x) * 8;
    float4 a = *(const float4*)(Wg + idx);
    float4 b = *(const float4*)(Wg + idx + 4);
    uint16_t o[8];
    o[0]=f32_to_bf16(a.x); o[1]=f32_to_bf16(a.y); o[2]=f32_to_bf16(a.z); o[3]=f32_to_bf16(a.w);
    o[4]=f32_to_bf16(b.x); o[5]=f32_to_bf16(b.y); o[6]=f32_to_bf16(b.z); o[7]=f32_to_bf16(b.w);
    *(short8*)(W2 + idx) = *(short8*)o;
}

// x[b,c,h,w] f32  ->  xT[r][q][rg=b*16+h4][w16][c] bf16  (67 MB)
// block: (c-tile, h, b); 64c x 64w tile through LDS.  ~at BW roofline.
__global__ __launch_bounds__(256)
void xt_cvt(const float* __restrict__ x, uint16_t* __restrict__ xT) {
    const int c0 = blockIdx.x * 64;
    const int h  = blockIdx.y;
    const int b  = blockIdx.z;
    const int r = h & 3, h4 = h >> 2, rg = b * 16 + h4;
    __shared__ float L[64][65];
    const int tid = threadIdx.x;
    const int wr = tid & 15;        // w float4 chunk
    const int cr = tid >> 4;        // c row (16 per iter)
    const float* src = x + (((size_t)b * CS + c0 + cr) * 64 + h) * 64 + wr * 4;
    #pragma unroll
    for (int it = 0; it < 4; ++it) {
        float4 v = *(const float4*)(src + (size_t)it * 16 * HW);
        L[cr + it * 16][wr * 4 + 0] = v.x;
        L[cr + it * 16][wr * 4 + 1] = v.y;
        L[cr + it * 16][wr * 4 + 2] = v.z;
        L[cr + it * 16][wr * 4 + 3] = v.w;
    }
    __syncthreads();
    const int orow = tid >> 2;            // 0..63
    const int q = orow >> 4, w16 = orow & 15;
    const int cc = (tid & 3) * 16;
    const int w = w16 * 4 + q;
    uint16_t tmp[16];
    #pragma unroll
    for (int i = 0; i < 16; ++i) tmp[i] = f32_to_bf16(L[cc + i][w]);
    uint16_t* dst = xT + ((((size_t)(r * 4 + q) * 256 + rg) * 16 + w16) * 512 + c0 + cc);
    *(short8*)(dst)     = *(short8*)(tmp);
    *(short8*)(dst + 8) = *(short8*)(tmp + 8);
}

__global__ __launch_bounds__(512, 2)
void gwl_main(const uint16_t* __restrict__ W2, const uint16_t* __restrict__ xT,
              float* __restrict__ out) {
    const int nb = blockIdx.x;   // pixel-row block: rows 8*nb..8*nb+7 of (b*16+h4)
    const int mb = blockIdx.y;   // out-channel block (128 rows)
    const int r  = blockIdx.z;   // h%4 phase
    const int m0 = mb * MT;

    // LDS: 2 x (As 32KB + Bs 32KB), both glds-linear 64B rows, k-chunk
    // XOR-swizzled via source. T (epilogue) aliases buffer 0.
    __shared__ __align__(16) unsigned char smem[2 * BUFB];
    float* T = (float*)smem;

    const int tid  = threadIdx.x;
    const int lane = tid & 63;
    const int wave = tid >> 6;      // 0..7
    const int q    = wave & 3;      // w%4 phase this wave computes
    const int mw   = wave >> 2;     // m-half (64 rows)
    const int lr = lane & 15, qd = lane >> 4;

    // glds lane decomposition: lane -> (lrow = lane>>2, slot = lane&3)
    // stored slot s at LDS row n holds global k-chunk s ^ ((n>>1)&3);
    // (n>>1)&3 == (lane>>3)&3 for n = 16t + lrow.
    const int lrow = lane >> 2;
    const int swz  = ((lane & 3) ^ ((lane >> 3) & 3)) * 8;   // elements

    const uint16_t* abase = W2 + ((size_t)(r * 4 + q) * CT + m0 + mw * 64) * CS;
    // Bs rows n = mw*64 + t*16 + lrow -> rho = mw*4 + t, w16 = lrow,
    // rg = nb*8 + rho.
    const uint16_t* bbase = xT + (((size_t)(r * 4 + q) * 256 + nb * 8 + mw * 4) * 16) * 512;

    auto stage = [&](int k0, int bufn) {
        uint16_t* As = (uint16_t*)(smem + bufn * BUFB) + (q * 128 + mw * 64) * 32;
        uint16_t* Bs = (uint16_t*)(smem + bufn * BUFB + ABYTES) + (q * 128 + mw * 64) * 32;
        #pragma unroll
        for (int t = 0; t < 4; ++t) {
            const uint16_t* asrc = abase + (size_t)(t * 16 + lrow) * CS + k0 + swz;
            __builtin_amdgcn_global_load_lds(
                (const __attribute__((address_space(1))) void*)asrc,
                (__attribute__((address_space(3))) void*)(As + t * 512), 16, 0, 0);
        }
        #pragma unroll
        for (int t = 0; t < 4; ++t) {
            const uint16_t* bsrc = bbase + ((size_t)t * 16 + lrow) * 512 + k0 + swz;
            __builtin_amdgcn_global_load_lds(
                (const __attribute__((address_space(1))) void*)bsrc,
                (__attribute__((address_space(3))) void*)(Bs + t * 512), 16, 0, 0);
        }
    };

    f32x4 acc[4][8] = {};

    // prologue: tiles 0 and 1 in flight; wait tile 0 (8 newest stay in flight)
    stage(0, 0);
    stage(BK, 1);
    asm volatile("s_waitcnt vmcnt(8)" ::: "memory");
    __builtin_amdgcn_s_barrier();

    const int rdswz = (qd ^ ((lr >> 1) & 3)) * 8;
    for (int k = 0; k < 16; ++k) {
        const int buf = k & 1;
        const uint16_t* Asq = (const uint16_t*)(smem + buf * BUFB)
                              + (q * 128 + mw * 64) * 32;
        const uint16_t* Bsq = (const uint16_t*)(smem + buf * BUFB + ABYTES)
                              + q * 128 * 32;
        short8 afr[4], bfr[8];
        #pragma unroll
        for (int i = 0; i < 4; ++i)
            afr[i] = *(const short8*)(Asq + (i * 16 + lr) * 32 + rdswz);
        #pragma unroll
        for (int j = 0; j < 8; ++j)
            bfr[j] = *(const short8*)(Bsq + (j * 16 + lr) * 32 + rdswz);

        // MFMA half-A (j=0..3): compiler-scheduled fine lgkmcnt interleave
        // hides the ds_read latency (no forced drain before compute).
        __builtin_amdgcn_s_setprio(1);
        #pragma unroll
        for (int i = 0; i < 4; ++i)
            #pragma unroll
            for (int j = 0; j < 4; ++j)
                acc[i][j] = __builtin_amdgcn_mfma_f32_16x16x32_bf16(
                    afr[i], bfr[j], acc[i][j], 0, 0, 0);
        __builtin_amdgcn_s_setprio(0);

        // Cross-wave safety: all 12 ds_reads of buf retired before any wave
        // overwrites buf (Bs is shared by the mw-pair).
        asm volatile("s_waitcnt lgkmcnt(0)" ::: "memory");
        __builtin_amdgcn_s_barrier();
        __builtin_amdgcn_sched_barrier(0);     // keep half-B below the barrier
        if (k < 14) stage((k + 2) * BK, buf);  // buf free; 2-step glds prefetch

        // MFMA half-B (j=4..7): overlaps glds issue of tile k+2.
        __builtin_amdgcn_s_setprio(1);
        #pragma unroll
        for (int i = 0; i < 4; ++i)
            #pragma unroll
            for (int j = 4; j < 8; ++j)
                acc[i][j] = __builtin_amdgcn_mfma_f32_16x16x32_bf16(
                    afr[i], bfr[j], acc[i][j], 0, 0, 0);
        __builtin_amdgcn_s_setprio(0);

        if (k < 15) {
            // retire glds(k+1) (8 oldest); glds(k+2) stays in flight (T4).
            if (k < 14) asm volatile("s_waitcnt vmcnt(8)" ::: "memory");
            else        asm volatile("s_waitcnt vmcnt(0)" ::: "memory");
            __builtin_amdgcn_s_barrier();
        }
    }

    // ---- epilogue: LDS transpose -> full-line float4 stores
    // acc[i][j][g]: m = m0 + mw*64 + i*16 + qd*4+g, pixel n = j*16+lr
    //   -> rho = j, w16 = lr, w = lr*4 + q. chunk ic = mw*4 + i.
    const int m16s = tid >> 5;        // 0..15
    const int rs   = (tid >> 2) & 7;  // 0..7
    const int ws   = (tid & 3) * 16;
    const int rgs  = nb * NR + rs;
    const int obb  = rgs >> 4;
    const int oh4  = rgs & 15;
    #pragma unroll
    for (int ic = 0; ic < 8; ++ic) {
        __syncthreads();
        if (mw == (ic >> 2)) {
            const int i = ic & 3;
            #pragma unroll
            for (int j = 0; j < 8; ++j)
                #pragma unroll
                for (int g = 0; g < 4; ++g)
                    T[((qd * 4 + g) * 8 + j) * 68 + lr * 4 + q] = acc[i][j][g];
        }
        __syncthreads();
        float* op = out + ((size_t)obb * CT + m0 + ic * 16 + m16s) * HW
                        + (oh4 * 4 + r) * 64 + ws;
        const float* tp = T + (m16s * 8 + rs) * 68 + ws;
        #pragma unroll
        for (int c = 0; c < 4; ++c)
            ((float4*)op)[c] = ((const float4*)tp)[c];
    }
}

// ---------- fallback (workspace too small): round-2 self-contained kernel ----
#define BPITCH 40
#define FBUFB 73728

__global__ __launch_bounds__(512, 2)
void gwl_fb(const float* __restrict__ x, const float* __restrict__ Wg,
            float* __restrict__ out) {
    const int nb = blockIdx.x, mb = blockIdx.y, r = blockIdx.z;
    const int m0 = mb * MT;
    __shared__ __align__(16) unsigned char smem[2 * FBUFB];
    float* T = (float*)smem;
    const int tid = threadIdx.x, lane = tid & 63, wave = tid >> 6;
    const int q = wave & 3, mw = wave >> 2;
    const int lr = lane & 15, qd = lane >> 4;
    const int w16 = tid & 15, rho = (tid >> 4) & 7, kw = tid >> 7;
    const int rg = nb * NR + rho, bb = rg >> 4, h4 = rg & 15;
    const float* bbase = x + (size_t)bb * CS * HW
                           + (size_t)((h4 * 4 + r) * 64 + w16 * 4);
    float4 breg[8];
    auto loadB = [&](int k0) {
        const float* p = bbase + (size_t)(k0 + kw * 8) * HW;
        #pragma unroll
        for (int cc = 0; cc < 8; ++cc) breg[cc] = *(const float4*)(p + (size_t)cc * HW);
    };
    auto writeB = [&](uint16_t* BsD) {
        #pragma unroll
        for (int qq = 0; qq < 4; ++qq) {
            uint16_t tmp[8];
            #pragma unroll
            for (int cc = 0; cc < 8; ++cc)
                tmp[cc] = f32_to_bf16(((const float*)&breg[cc])[qq]);
            *(short8*)(BsD + (qq * 128 + rho * 16 + w16) * BPITCH + kw * 8) = *(short8*)tmp;
        }
    };
    auto stageA = [&](int k0, uint16_t* AsD) {
        const int qa = tid >> 7, rem = tid & 127;
        const int ka = rem & 7, ma = rem >> 3;
        const float* ap = Wg + ((size_t)(r * 4 + qa) * CT + m0 + ma) * CS + k0 + ka * 4;
        const int kc = (((ka >> 1) ^ ((ma >> 1) & 3)) * 8) + (ka & 1) * 4;
        #pragma unroll
        for (int it = 0; it < 8; ++it) {
            float4 v = *(const float4*)(ap + (size_t)it * 16 * CS);
            uint16_t tmp[4] = {f32_to_bf16(v.x), f32_to_bf16(v.y),
                               f32_to_bf16(v.z), f32_to_bf16(v.w)};
            *(uint64_t*)(AsD + (qa * 128 + ma + it * 16) * 32 + kc) =
                *(const uint64_t*)tmp;
        }
    };
    f32x4 acc[4][8] = {};
    {
        uint16_t* As0 = (uint16_t*)smem;
        uint16_t* Bs0 = (uint16_t*)(smem + 32768);
        loadB(0);
        stageA(0, As0);
        writeB(Bs0);
        loadB(BK);
        __syncthreads();
    }
    for (int k = 0; k < 16; ++k) {
        const uint16_t* Asq = (const uint16_t*)(smem + (k & 1) * FBUFB)
                              + (q * 128 + mw * 64) * 32;
        const uint16_t* Bsq = (const uint16_t*)(smem + (k & 1) * FBUFB + 32768)
                              + q * 128 * BPITCH;
        short8 afr[4], bfr[8];
        #pragma unroll
        for (int i = 0; i < 4; ++i)
            afr[i] = *(const short8*)(Asq + (i * 16 + lr) * 32
                                      + ((qd ^ ((lr >> 1) & 3)) * 8));
        #pragma unroll
        for (int j = 0; j < 8; ++j)
            bfr[j] = *(const short8*)(Bsq + (j * 16 + lr) * BPITCH + qd * 8);
        if (k < 15) {
            uint16_t* AsN = (uint16_t*)(smem + ((k + 1) & 1) * FBUFB);
            uint16_t* BsN = (uint16_t*)(smem + ((k + 1) & 1) * FBUFB + 32768);
            stageA((k + 1) * BK, AsN);
            writeB(BsN);
            if (k < 14) loadB((k + 2) * BK);
        }
        #pragma unroll
        for (int i = 0; i < 4; ++i)
            #pragma unroll
            for (int j = 0; j < 8; ++j)
                acc[i][j] = __builtin_amdgcn_mfma_f32_16x16x32_bf16(
                    afr[i], bfr[j], acc[i][j], 0, 0, 0);
        if (k < 15) {
            asm volatile("s_waitcnt vmcnt(0)" ::: "memory");
            asm volatile("s_waitcnt lgkmcnt(0)" ::: "memory");
            __builtin_amdgcn_s_barrier();
        }
    }
    const int m16s = tid >> 5, rs = (tid >> 2) & 7, ws = (tid & 3) * 16;
    const int rgs = nb * NR + rs, obb = rgs >> 4, oh4 = rgs & 15;
    #pragma unroll
    for (int ic = 0; ic < 8; ++ic) {
        __syncthreads();
        if (mw == (ic >> 2)) {
            const int i = ic & 3;
            #pragma unroll
            for (int j = 0; j < 8; ++j)
                #pragma unroll
                for (int g = 0; g < 4; ++g)
                    T[((qd * 4 + g) * 8 + j) * 68 + lr * 4 + q] = acc[i][j][g];
        }
        __syncthreads();
        float* op = out + ((size_t)obb * CT + m0 + ic * 16 + m16s) * HW
                        + (oh4 * 4 + r) * 64 + ws;
        const float* tp = T + (m16s * 8 + rs) * 68 + ws;
        #pragma unroll
        for (int c = 0; c < 4; ++c)
            ((float4*)op)[c] = ((const float4*)tp)[c];
    }
}

extern "C" void kernel_launch(void* const* d_in, const int* in_sizes, int n_in,
                              void* d_out, int out_size, void* d_ws, size_t ws_size,
                              hipStream_t stream) {
    const float* x  = (const float*)d_in[0];
    const float* Wg = (const float*)d_in[1];
    float* out = (float*)d_out;
    dim3 grid(32, 4, 4);   // nb fastest: mb siblings (id stride 32) share an XCD
    const size_t w2_elems = (size_t)16 * 512 * 512;             // 8 MB
    const size_t xt_elems = (size_t)4 * 4 * 256 * 16 * 512;     // 67 MB
    if (ws_size >= (w2_elems + xt_elems) * 2) {
        uint16_t* W2 = (uint16_t*)d_ws;
        uint16_t* xT = (uint16_t*)d_ws + w2_elems;
        w2_cvt<<<2048, 256, 0, stream>>>(Wg, W2);
        xt_cvt<<<dim3(8, 64, 16), 256, 0, stream>>>(x, xT);
        gwl_main<<<grid, 512, 0, stream>>>(W2, xT, out);
    } else {
        gwl_fb<<<grid, 512, 0, stream>>>(x, Wg, out);
    }
}